// Round 3
// baseline (131.941 us; speedup 1.0000x reference)
//
#include <hip/hip_runtime.h>
#include <hip/hip_bf16.h>

// Problem constants
#define BATCH 8
#define SEQ   2048
#define DEMB  1024
#define HD    64
#define NROWS (BATCH * SEQ)   // 16384

typedef __attribute__((ext_vector_type(8))) short bf16x8;  // 8 bf16 in 4 VGPRs
typedef __attribute__((ext_vector_type(4))) float f32x4;

// fp32 -> bf16 round-to-nearest-even (bit pattern as short)
__device__ inline short f2b(float f) {
    unsigned u = __builtin_bit_cast(unsigned, f);
    unsigned r = (u + 0x7fffu + ((u >> 16) & 1u)) >> 16;
    return (short)r;
}

// ---------------------------------------------------------------------------
// Kernel 0: prep — Wt[n][d] = W(d,n) as bf16 (n: 0..63 Wq, 64..127 Wk, 128..191 Wv)
//           bias[192] fp32 concat
// ---------------------------------------------------------------------------
__global__ void prep_kernel(const float* __restrict__ Wq, const float* __restrict__ bq,
                            const float* __restrict__ Wk, const float* __restrict__ bk,
                            const float* __restrict__ Wv, const float* __restrict__ bv,
                            short* __restrict__ Wt, float* __restrict__ bias) {
    int idx = blockIdx.x * blockDim.x + threadIdx.x;   // 0 .. 192*1024-1
    if (idx < 192 * 1024) {
        int n = idx >> 10;
        int d = idx & 1023;
        const float* W = (n < 64) ? Wq : (n < 128) ? Wk : Wv;
        int nn = n & 63;
        Wt[idx] = f2b(W[(size_t)d * 64 + nn]);
    }
    if (idx < 192) {
        const float* bb = (idx < 64) ? bq : (idx < 128) ? bk : bv;
        bias[idx] = bb[idx & 63];
    }
}

// ---------------------------------------------------------------------------
// Kernel 1: fused QKV projection via MFMA bf16.
//   Grid: 256 blocks x 256 threads (4 waves). Wave handles 16 rows x 192 cols.
//   A frag: x[row][k0 + lg*8 .. +8] (fp32 -> bf16)
//   B frag: Wt[n][k0 + lg*8 .. +8] (contiguous bf16)
//   Writes Q,K row-major bf16 [16384][64]; V transposed Vt[b][64][2048] bf16.
// ---------------------------------------------------------------------------
__global__ __launch_bounds__(256) void proj_kernel(const float* __restrict__ x,
        const short* __restrict__ Wt, const float* __restrict__ bias,
        short* __restrict__ Qo, short* __restrict__ Ko, short* __restrict__ Vto) {
    const int wid  = threadIdx.x >> 6;
    const int lane = threadIdx.x & 63;
    const int l15  = lane & 15;
    const int lg   = lane >> 4;
    const int t0   = blockIdx.x * 64 + wid * 16;   // wave's first global row
    const int row  = t0 + l15;

    const float* xr = x + (size_t)row * DEMB + lg * 8;
    const short* wp0 = Wt + (size_t)l15 * DEMB + lg * 8;

    f32x4 acc[12];
#pragma unroll
    for (int i = 0; i < 12; ++i) acc[i] = (f32x4){0.f, 0.f, 0.f, 0.f};

    for (int k0 = 0; k0 < DEMB; k0 += 32) {
        // A fragment: 8 consecutive fp32 -> bf16
        f32x4 xa = *(const f32x4*)(xr + k0);
        f32x4 xb = *(const f32x4*)(xr + k0 + 4);
        bf16x8 af;
        af[0] = f2b(xa[0]); af[1] = f2b(xa[1]); af[2] = f2b(xa[2]); af[3] = f2b(xa[3]);
        af[4] = f2b(xb[0]); af[5] = f2b(xb[1]); af[6] = f2b(xb[2]); af[7] = f2b(xb[3]);
        const short* wp = wp0 + k0;
#pragma unroll
        for (int nf = 0; nf < 12; ++nf) {
            bf16x8 bfv = *(const bf16x8*)(wp + (size_t)nf * 16 * DEMB);
            acc[nf] = __builtin_amdgcn_mfma_f32_16x16x32_bf16(af, bfv, acc[nf], 0, 0, 0);
        }
    }

    // Epilogue: +bias, write bf16. C/D layout: col = l15, row = lg*4 + j.
#pragma unroll
    for (int nf = 0; nf < 12; ++nf) {
        int n = nf * 16 + l15;
        float bv_ = bias[n];
#pragma unroll
        for (int j = 0; j < 4; ++j) {
            int t = t0 + lg * 4 + j;
            short v = f2b(acc[nf][j] + bv_);
            if (n < 64) {
                Qo[(size_t)t * HD + n] = v;
            } else if (n < 128) {
                Ko[(size_t)t * HD + (n - 64)] = v;
            } else {
                int b = t >> 11, tt = t & 2047, d = n - 128;
                Vto[((size_t)b * HD + d) * SEQ + tt] = v;
            }
        }
    }
}

// ---------------------------------------------------------------------------
// Kernel 2: causal flash attention.
//   1024 waves total (256 blocks x 4 waves); wave = (batch b, 16 q-rows).
//   Work-balancing remap pairs chunk c with 127-c.
//   KVBLK = 32: S = 2 nfrags x 2 ksteps MFMA; online softmax; PV via
//   LDS-transposed P (A-frag) x Vt rows (B-frag), 4 d-frags.
// ---------------------------------------------------------------------------
__global__ __launch_bounds__(256) void attn_kernel(const short* __restrict__ Q,
        const short* __restrict__ K, const short* __restrict__ Vt,
        float* __restrict__ out) {
    __shared__ short plds[4][16][32];

    const int wid  = threadIdx.x >> 6;
    const int lane = threadIdx.x & 63;
    const int l15  = lane & 15;
    const int lg   = lane >> 4;

    const int gw = blockIdx.x * 4 + wid;    // 0..1023
    const int b  = gw >> 7;
    const int c0 = gw & 127;
    const int c  = (c0 & 1) ? (127 - (c0 >> 1)) : (c0 >> 1);
    const int q0 = c * 16;                  // first q row (within batch)

    // Q fragments (held in registers for the whole kernel)
    const short* qbase = Q + ((size_t)(b * SEQ + q0 + l15)) * HD + lg * 8;
    bf16x8 qf0 = *(const bf16x8*)(qbase);
    bf16x8 qf1 = *(const bf16x8*)(qbase + 32);

    f32x4 o[4];
    float m[4], lsum[4];
#pragma unroll
    for (int df = 0; df < 4; ++df) o[df] = (f32x4){0.f, 0.f, 0.f, 0.f};
#pragma unroll
    for (int j = 0; j < 4; ++j) { m[j] = -1e30f; lsum[j] = 0.f; }

    const int ntile = (q0 + 16 + 31) >> 5;  // kv tiles covering [0, q0+16)
    const short* kbb = K  + (size_t)b * SEQ * HD;
    const short* vbb = Vt + (size_t)b * HD * SEQ;

    for (int tile = 0; tile < ntile; ++tile) {
        const int kv0 = tile * 32;

        // ---- S = Q K^T ----
        f32x4 s[2] = {(f32x4){0.f,0.f,0.f,0.f}, (f32x4){0.f,0.f,0.f,0.f}};
#pragma unroll
        for (int nf = 0; nf < 2; ++nf) {
            const short* kp = kbb + (size_t)(kv0 + nf * 16 + l15) * HD + lg * 8;
            bf16x8 kf0 = *(const bf16x8*)kp;
            bf16x8 kf1 = *(const bf16x8*)(kp + 32);
            s[nf] = __builtin_amdgcn_mfma_f32_16x16x32_bf16(qf0, kf0, s[nf], 0, 0, 0);
            s[nf] = __builtin_amdgcn_mfma_f32_16x16x32_bf16(qf1, kf1, s[nf], 0, 0, 0);
        }

        // ---- scale + causal mask ----
        float sv[2][4];
#pragma unroll
        for (int nf = 0; nf < 2; ++nf)
#pragma unroll
            for (int j = 0; j < 4; ++j) {
                int qr = q0 + lg * 4 + j;
                int kv = kv0 + nf * 16 + l15;
                float v = s[nf][j] * 0.125f;
                sv[nf][j] = (kv <= qr) ? v : -1e30f;
            }

        // ---- row max over the 32 kv of this tile (16-lane-group reduce) ----
        float mt[4];
#pragma unroll
        for (int j = 0; j < 4; ++j) mt[j] = fmaxf(sv[0][j], sv[1][j]);
#pragma unroll
        for (int sh = 1; sh < 16; sh <<= 1)
#pragma unroll
            for (int j = 0; j < 4; ++j) mt[j] = fmaxf(mt[j], __shfl_xor(mt[j], sh));

        // ---- online softmax update ----
        float p[2][4], rs[4];
#pragma unroll
        for (int j = 0; j < 4; ++j) {
            float mn = fmaxf(m[j], mt[j]);
            float sf = __expf(m[j] - mn);
            m[j] = mn;
            lsum[j] *= sf;
#pragma unroll
            for (int df = 0; df < 4; ++df) o[df][j] *= sf;
            p[0][j] = __expf(sv[0][j] - mn);
            p[1][j] = __expf(sv[1][j] - mn);
            rs[j] = p[0][j] + p[1][j];
        }
#pragma unroll
        for (int sh = 1; sh < 16; sh <<= 1)
#pragma unroll
            for (int j = 0; j < 4; ++j) rs[j] += __shfl_xor(rs[j], sh);
#pragma unroll
        for (int j = 0; j < 4; ++j) lsum[j] += rs[j];

        // ---- transpose P through LDS (per-wave buffer, no barrier needed) ----
#pragma unroll
        for (int nf = 0; nf < 2; ++nf)
#pragma unroll
            for (int j = 0; j < 4; ++j)
                plds[wid][lg * 4 + j][nf * 16 + l15] = f2b(p[nf][j]);

        bf16x8 pa = *(const bf16x8*)&plds[wid][l15][lg * 8];

        // ---- O += P V ----
#pragma unroll
        for (int df = 0; df < 4; ++df) {
            const short* vp = vbb + (size_t)(df * 16 + l15) * SEQ + kv0 + lg * 8;
            bf16x8 vf = *(const bf16x8*)vp;
            o[df] = __builtin_amdgcn_mfma_f32_16x16x32_bf16(pa, vf, o[df], 0, 0, 0);
        }
    }

    // ---- epilogue: out = O / l ----
#pragma unroll
    for (int df = 0; df < 4; ++df) {
        int d = df * 16 + l15;
#pragma unroll
        for (int j = 0; j < 4; ++j) {
            int t = q0 + lg * 4 + j;
            out[((size_t)(b * SEQ + t)) * HD + d] = o[df][j] / lsum[j];
        }
    }
}

// ---------------------------------------------------------------------------
extern "C" void kernel_launch(void* const* d_in, const int* in_sizes, int n_in,
                              void* d_out, int out_size, void* d_ws, size_t ws_size,
                              hipStream_t stream) {
    const float* x  = (const float*)d_in[0];
    const float* Wq = (const float*)d_in[1];
    const float* bq = (const float*)d_in[2];
    const float* Wk = (const float*)d_in[3];
    const float* bk = (const float*)d_in[4];
    const float* Wv = (const float*)d_in[5];
    const float* bv = (const float*)d_in[6];
    float* out = (float*)d_out;

    char* ws = (char*)d_ws;
    // Workspace layout (bytes):
    //   Wt   bf16 [192][1024]          @ 0        (393216)
    //   bias f32  [192]                @ 393216   (768)
    //   Q    bf16 [16384][64]          @ 394240   (2097152)
    //   K    bf16 [16384][64]          @ 2491392  (2097152)
    //   Vt   bf16 [8][64][2048]        @ 4588544  (2097152)
    short* Wt   = (short*)(ws);
    float* bias = (float*)(ws + 393216);
    short* Qb   = (short*)(ws + 394240);
    short* Kb   = (short*)(ws + 394240 + 2097152);
    short* Vtb  = (short*)(ws + 394240 + 2 * 2097152);

    hipLaunchKernelGGL(prep_kernel, dim3(768), dim3(256), 0, stream,
                       Wq, bq, Wk, bk, Wv, bv, Wt, bias);
    hipLaunchKernelGGL(proj_kernel, dim3(256), dim3(256), 0, stream,
                       x, Wt, bias, Qb, Kb, Vtb);
    hipLaunchKernelGGL(attn_kernel, dim3(256), dim3(256), 0, stream,
                       Qb, Kb, Vtb, out);
}